// Round 2
// baseline (879.184 us; speedup 1.0000x reference)
//
#include <hip/hip_runtime.h>
#include <hip/hip_bf16.h>
#include <math.h>

#define N_NODES 100000
#define N_EDGES 1600000
#define NF 128
#define NH 4
#define ND 16
#define GAT_ALPHA 0.2f

#define BSHIFT 8                      // bucket = dst >> 8 (256 nodes per bucket)
#define NBK 391                       // ceil(100000 / 256)
#define CAPB 5120                     // slab capacity per bucket (E[edges]=4096, sigma=64)
#define EPB 8192                      // edges per placement block
#define EBLK 196                      // placement blocks (ceil(E / EPB))
#define PBLK 782                      // projection blocks
#define NTILES ((N_NODES + 63) / 64)  // 1563

typedef __attribute__((ext_vector_type(8))) __bf16 bf16x8;
typedef __attribute__((ext_vector_type(4))) float f32x4;

#define PADK 136                      // bf16 row stride (272B), breaks bank stride
#define ACC_STRIDE 68                 // 64 dims + 4 den; 68 dwords -> dn*68 % 32 = dn*4 spreads quarters

// ---------------------------------------------------------------------------
// Fused kernel, role by blockIdx:
//   blocks [0, EBLK)      : bucket placement of edges into fixed slabs
//   blocks [EBLK, EBLK+PBLK): MFMA projection (A-frags direct from global)
// (unchanged from the 212 µs baseline — measured 58-67 µs, latency-bound)
// ---------------------------------------------------------------------------
__global__ __launch_bounds__(256) void k_fused(
    const float* __restrict__ h, const float* __restrict__ W,
    const float* __restrict__ Wb, const float* __restrict__ a,
    const float* __restrict__ ab, const int* __restrict__ src,
    const int* __restrict__ dst, int* __restrict__ gcur,
    uint* __restrict__ sb, __hip_bfloat16* __restrict__ Whb,
    float* __restrict__ es, float* __restrict__ ed)
{
    __shared__ __align__(16) __hip_bfloat16 Bt[80 * PADK];  // 21.8 KB (project)
    __shared__ int hist[NBK];                               // 1.6 KB (place)
    __shared__ int cur[NBK];                                // 1.6 KB (place)

    const int tid = threadIdx.x;

    if (blockIdx.x < EBLK) {
        // ---------------- role: bucket placement ------------------------
        const int base = blockIdx.x * EPB;
        const int lim = min(EPB, N_EDGES - base);

        for (int i = tid; i < NBK; i += 256) hist[i] = 0;
        __syncthreads();
        for (int i = tid; i < lim; i += 256)
            atomicAdd(&hist[dst[base + i] >> BSHIFT], 1);
        __syncthreads();
        for (int i = tid; i < NBK; i += 256) {
            int v = hist[i];
            cur[i] = v ? atomicAdd(&gcur[i], v) : 0;
        }
        __syncthreads();
        for (int i = tid; i < lim; i += 256) {
            int d = dst[base + i];
            int bk = d >> BSHIFT;
            int pos = atomicAdd(&cur[bk], 1);            // LDS returning atomic
            if (pos < CAPB)
                sb[bk * CAPB + pos] = (uint)(src[base + i] | ((d & 255) << 17));
        }
        return;
    }

    // ------------------- role: MFMA projection --------------------------
    const int pb = blockIdx.x - EBLK;    // 0..PBLK-1
    const int wv = tid >> 6;
    const int l = tid & 63;
    const int m = l & 15;
    const int quad = l >> 4;

    // stage B (cols 0..63 = W; 64..67 = W·a1; 72..75 = W·a2), once per block
    for (int idx = tid; idx < 64 * 128; idx += 256) {
        int d = idx & 15, hh = (idx >> 4) & 3, f = idx >> 6;
        Bt[(hh * 16 + d) * PADK + f] =
            __float2bfloat16(W[hh * (NF * ND) + f * ND + d]);
    }
    for (int idx = tid; idx < 128 * 4; idx += 256) {
        int f = idx >> 2, hh = idx & 3;
        float s1 = 0.f, s2 = 0.f;
        #pragma unroll
        for (int d = 0; d < 16; d++) {
            float wv_ = W[hh * (NF * ND) + f * ND + d];
            s1 = fmaf(wv_, a[hh * 32 + d], s1);
            s2 = fmaf(wv_, a[hh * 32 + 16 + d], s2);
        }
        Bt[(64 + hh) * PADK + f] = __float2bfloat16(s1);
        Bt[(72 + hh) * PADK + f] = __float2bfloat16(s2);
    }
    for (int idx = tid; idx < 8 * 128; idx += 256) {
        int f = idx & 127, c = idx >> 7;
        int n = (c < 4) ? (68 + c) : (72 + c);
        Bt[n * PADK + f] = __float2bfloat16(0.f);
    }

    float wb4[4];
    #pragma unroll
    for (int t = 0; t < 4; t++) wb4[t] = Wb[t * 16 + m];
    float eb = 0.f;
    if (m < 4) {
        #pragma unroll
        for (int d = 0; d < 16; d++) eb = fmaf(Wb[m * 16 + d], a[m * 32 + d], eb);
    } else if (m >= 8 && m < 12) {
        int hh = m - 8;
        #pragma unroll
        for (int d = 0; d < 16; d++)
            eb = fmaf(Wb[hh * 16 + d], a[hh * 32 + 16 + d], eb);
        eb += ab[hh];
    }
    __syncthreads();   // Bt visible; no per-tile barriers needed after this

    for (int tile = pb; tile < NTILES; tile += PBLK) {
        const int node = tile * 64 + wv * 16 + m;   // A row this lane serves
        const bool ok = node < N_NODES;
        const float4* hrow = (const float4*)(h + (size_t)(ok ? node : 0) * NF);

        f32x4 acc[5];
        #pragma unroll
        for (int t = 0; t < 5; t++) acc[t] = (f32x4){0.f, 0.f, 0.f, 0.f};

        #pragma unroll
        for (int kk = 0; kk < 4; kk++) {
            // A-frag direct from global: cols kk*32 + quad*8 .. +8
            bf16x8 af;
            if (ok) {
                float4 v0 = hrow[kk * 8 + quad * 2];
                float4 v1 = hrow[kk * 8 + quad * 2 + 1];
                af[0] = (__bf16)v0.x; af[1] = (__bf16)v0.y;
                af[2] = (__bf16)v0.z; af[3] = (__bf16)v0.w;
                af[4] = (__bf16)v1.x; af[5] = (__bf16)v1.y;
                af[6] = (__bf16)v1.z; af[7] = (__bf16)v1.w;
            } else {
                #pragma unroll
                for (int j = 0; j < 8; j++) af[j] = (__bf16)0.f;
            }
            #pragma unroll
            for (int t = 0; t < 5; t++) {
                bf16x8 bf = *(const bf16x8*)&Bt[(t * 16 + m) * PADK + kk * 32 + quad * 8];
                acc[t] = __builtin_amdgcn_mfma_f32_16x16x32_bf16(af, bf, acc[t], 0, 0, 0);
            }
        }

        // epilogue: D layout col=lane&15, row=quad*4+reg
        const int nodeb = tile * 64 + wv * 16 + quad * 4;
        #pragma unroll
        for (int r = 0; r < 4; r++) {
            int n = nodeb + r;
            if (n < N_NODES) {
                #pragma unroll
                for (int t = 0; t < 4; t++)
                    Whb[n * 64 + t * 16 + m] = __float2bfloat16(acc[t][r] + wb4[t]);
                float ev = acc[4][r] + eb;
                if (m < 4) es[n * 4 + m] = ev;
                else if (m >= 8 && m < 12) ed[n * 4 + (m - 8)] = ev;
            }
        }
    }
}

// ---------------------------------------------------------------------------
// Replaces k_csr + k_gather. One block per bucket (256 dst nodes).
// Per-bucket accumulators live in LDS: [256 nodes][64 dims + 4 den] f32.
// Stream the UNSORTED slab (coalesced), 16 lanes per edge (4 dims/lane),
// accumulate p * Whb[src] with ds_add_f32.  No per-node sort needed.
// 512 threads, 72 KB LDS -> 2 blocks/CU, 16 waves/CU.
// ---------------------------------------------------------------------------
__global__ __launch_bounds__(512) void k_acc(
    const uint* __restrict__ sb, const int* __restrict__ gcur,
    const __hip_bfloat16* __restrict__ Whb, const float* __restrict__ es,
    const float* __restrict__ ed, float* __restrict__ out)
{
    __shared__ float accf[256 * ACC_STRIDE];   // 69,632 B
    __shared__ float edl[256 * 4];             // 4 KB: ed for this bucket's nodes

    const int b = blockIdx.x;
    const int t = threadIdx.x;
    const int l = t & 63;
    const int wid = t >> 6;          // 0..7
    const int r = l & 15;            // lane-in-quarter: dims 4r..4r+3
    const int q = l >> 4;            // quarter = which edge of the 4-group
    const int hh = r >> 2;           // head of dims 4r..4r+3

    // zero accumulators (float4 writes)
    float4* az = (float4*)accf;
    for (int i = t; i < 256 * ACC_STRIDE / 4; i += 512)
        az[i] = make_float4(0.f, 0.f, 0.f, 0.f);
    if (t < 256) {
        int node = b * 256 + t;
        ((float4*)edl)[t] = (node < N_NODES) ? ((const float4*)ed)[node]
                                             : make_float4(0.f, 0.f, 0.f, 0.f);
    }
    __syncthreads();

    const int ebase = b * CAPB;
    const int ecnt = min(gcur[b], CAPB);
    const uint2* Wu2 = (const uint2*)Whb;

    // 8 waves x 4 quarters x 4-unroll = 128 edges per block-iteration
    for (int i0 = wid * 16; i0 < ecnt; i0 += 128) {
        uint v[4];
        #pragma unroll
        for (int u = 0; u < 4; u++) {
            int ei = i0 + u * 4 + q;
            v[u] = (ei < ecnt) ? sb[ebase + ei] : 0xFFFFFFFFu;   // sentinel
        }
        float p[4]; uint2 w[4]; int dn[4];
        #pragma unroll
        for (int u = 0; u < 4; u++) {
            bool ok = (v[u] != 0xFFFFFFFFu);
            int s = ok ? (int)(v[u] & 0x1FFFFu) : 0;
            dn[u] = ok ? (int)(v[u] >> 17) : 0;
            float x = es[s * 4 + hh] + edl[dn[u] * 4 + hh];
            p[u] = ok ? __expf(fmaxf(x, GAT_ALPHA * x)) : 0.f;
            w[u] = Wu2[s * 16 + r];
        }
        #pragma unroll
        for (int u = 0; u < 4; u++) {
            float* ap = &accf[dn[u] * ACC_STRIDE + r * 4];
            atomicAdd(ap + 0, p[u] * __uint_as_float(w[u].x << 16));
            atomicAdd(ap + 1, p[u] * __uint_as_float(w[u].x & 0xffff0000u));
            atomicAdd(ap + 2, p[u] * __uint_as_float(w[u].y << 16));
            atomicAdd(ap + 3, p[u] * __uint_as_float(w[u].y & 0xffff0000u));
            if ((r & 3) == 0)
                atomicAdd(&accf[dn[u] * ACC_STRIDE + 64 + hh], p[u]);
        }
    }
    __syncthreads();

    // normalize + write out: 4096 (node,r) pairs over 512 threads
    for (int idx = t; idx < 256 * 16; idx += 512) {
        int ln = idx >> 4;
        int rr = idx & 15;
        int node = b * 256 + ln;
        if (node < N_NODES) {
            float4 acc = *(float4*)&accf[ln * ACC_STRIDE + rr * 4];
            float den = accf[ln * ACC_STRIDE + 64 + (rr >> 2)];
            float inv = 1.f / fmaxf(den, 1e-9f);   // deg==0 -> 0, matches ref
            ((float4*)out)[node * 16 + rr] =
                make_float4(acc.x * inv, acc.y * inv, acc.z * inv, acc.w * inv);
        }
    }
}

// ---------------------------------------------------------------------------
extern "C" void kernel_launch(void* const* d_in, const int* in_sizes, int n_in,
                              void* d_out, int out_size, void* d_ws, size_t ws_size,
                              hipStream_t stream)
{
    const float* h  = (const float*)d_in[0];
    const float* W  = (const float*)d_in[1];
    const float* Wb = (const float*)d_in[2];
    const float* a  = (const float*)d_in[3];
    const float* ab = (const float*)d_in[4];
    const int* src  = (const int*)d_in[5];
    const int* dst  = (const int*)d_in[6];
    float* out = (float*)d_out;

    char* w = (char*)d_ws;
    __hip_bfloat16* Whb = (__hip_bfloat16*)w; w += (size_t)N_NODES * 64 * 2;  // 12.8 MB
    float* es      = (float*)w;  w += (size_t)N_NODES * 4 * 4;     // 1.6 MB
    float* ed      = (float*)w;  w += (size_t)N_NODES * 4 * 4;     // 1.6 MB
    uint* sb       = (uint*)w;   w += (size_t)NBK * CAPB * 4;      // 8.0 MB
    int* gcur      = (int*)w;    w += 512 * 4;
    // total ~24 MB

    hipMemsetAsync(gcur, 0, NBK * sizeof(int), stream);
    k_fused<<<EBLK + PBLK, 256, 0, stream>>>(h, W, Wb, a, ab, src, dst,
                                             gcur, sb, Whb, es, ed);
    k_acc<<<NBK, 512, 0, stream>>>(sb, gcur, Whb, es, ed, out);
}

// Round 3
// 204.310 us; speedup vs baseline: 4.3032x; 4.3032x over previous
//
#include <hip/hip_runtime.h>
#include <hip/hip_bf16.h>
#include <math.h>

#define N_NODES 100000
#define N_EDGES 1600000
#define NF 128
#define NH 4
#define ND 16
#define GAT_ALPHA 0.2f

#define BSHIFT 8                      // bucket = dst >> 8 (256 nodes per bucket)
#define NBK 391                       // ceil(100000 / 256)
#define CAPB 5120                     // slab capacity per bucket (E[edges]=4096, sigma=64)
#define CAPH 2816                     // per half-bucket LDS list capacity (mean 2048 + 17 sigma)
#define EPB 8192                      // edges per placement block
#define EBLK 196                      // placement blocks (ceil(E / EPB))
#define PBLK 782                      // projection blocks
#define NTILES ((N_NODES + 63) / 64)  // 1563

typedef __attribute__((ext_vector_type(8))) __bf16 bf16x8;
typedef __attribute__((ext_vector_type(4))) float f32x4;

#define PADK 136                      // bf16 row stride (272B), breaks bank stride

// ---------------------------------------------------------------------------
// Fused kernel, role by blockIdx:
//   blocks [0, EBLK)      : bucket placement of edges into fixed slabs
//   blocks [EBLK, EBLK+PBLK): MFMA projection (A-frags direct from global)
// (byte-identical to the 212 µs baseline — measured 58-67 µs, latency-bound)
// ---------------------------------------------------------------------------
__global__ __launch_bounds__(256) void k_fused(
    const float* __restrict__ h, const float* __restrict__ W,
    const float* __restrict__ Wb, const float* __restrict__ a,
    const float* __restrict__ ab, const int* __restrict__ src,
    const int* __restrict__ dst, int* __restrict__ gcur,
    uint* __restrict__ sb, __hip_bfloat16* __restrict__ Whb,
    float* __restrict__ es, float* __restrict__ ed)
{
    __shared__ __align__(16) __hip_bfloat16 Bt[80 * PADK];  // 21.8 KB (project)
    __shared__ int hist[NBK];                               // 1.6 KB (place)
    __shared__ int cur[NBK];                                // 1.6 KB (place)

    const int tid = threadIdx.x;

    if (blockIdx.x < EBLK) {
        // ---------------- role: bucket placement ------------------------
        const int base = blockIdx.x * EPB;
        const int lim = min(EPB, N_EDGES - base);

        for (int i = tid; i < NBK; i += 256) hist[i] = 0;
        __syncthreads();
        for (int i = tid; i < lim; i += 256)
            atomicAdd(&hist[dst[base + i] >> BSHIFT], 1);
        __syncthreads();
        for (int i = tid; i < NBK; i += 256) {
            int v = hist[i];
            cur[i] = v ? atomicAdd(&gcur[i], v) : 0;
        }
        __syncthreads();
        for (int i = tid; i < lim; i += 256) {
            int d = dst[base + i];
            int bk = d >> BSHIFT;
            int pos = atomicAdd(&cur[bk], 1);            // LDS returning atomic
            if (pos < CAPB)
                sb[bk * CAPB + pos] = (uint)(src[base + i] | ((d & 255) << 17));
        }
        return;
    }

    // ------------------- role: MFMA projection --------------------------
    const int pb = blockIdx.x - EBLK;    // 0..PBLK-1
    const int wv = tid >> 6;
    const int l = tid & 63;
    const int m = l & 15;
    const int quad = l >> 4;

    // stage B (cols 0..63 = W; 64..67 = W·a1; 72..75 = W·a2), once per block
    for (int idx = tid; idx < 64 * 128; idx += 256) {
        int d = idx & 15, hh = (idx >> 4) & 3, f = idx >> 6;
        Bt[(hh * 16 + d) * PADK + f] =
            __float2bfloat16(W[hh * (NF * ND) + f * ND + d]);
    }
    for (int idx = tid; idx < 128 * 4; idx += 256) {
        int f = idx >> 2, hh = idx & 3;
        float s1 = 0.f, s2 = 0.f;
        #pragma unroll
        for (int d = 0; d < 16; d++) {
            float wv_ = W[hh * (NF * ND) + f * ND + d];
            s1 = fmaf(wv_, a[hh * 32 + d], s1);
            s2 = fmaf(wv_, a[hh * 32 + 16 + d], s2);
        }
        Bt[(64 + hh) * PADK + f] = __float2bfloat16(s1);
        Bt[(72 + hh) * PADK + f] = __float2bfloat16(s2);
    }
    for (int idx = tid; idx < 8 * 128; idx += 256) {
        int f = idx & 127, c = idx >> 7;
        int n = (c < 4) ? (68 + c) : (72 + c);
        Bt[n * PADK + f] = __float2bfloat16(0.f);
    }

    float wb4[4];
    #pragma unroll
    for (int t = 0; t < 4; t++) wb4[t] = Wb[t * 16 + m];
    float eb = 0.f;
    if (m < 4) {
        #pragma unroll
        for (int d = 0; d < 16; d++) eb = fmaf(Wb[m * 16 + d], a[m * 32 + d], eb);
    } else if (m >= 8 && m < 12) {
        int hh = m - 8;
        #pragma unroll
        for (int d = 0; d < 16; d++)
            eb = fmaf(Wb[hh * 16 + d], a[hh * 32 + 16 + d], eb);
        eb += ab[hh];
    }
    __syncthreads();   // Bt visible; no per-tile barriers needed after this

    for (int tile = pb; tile < NTILES; tile += PBLK) {
        const int node = tile * 64 + wv * 16 + m;   // A row this lane serves
        const bool ok = node < N_NODES;
        const float4* hrow = (const float4*)(h + (size_t)(ok ? node : 0) * NF);

        f32x4 acc[5];
        #pragma unroll
        for (int t = 0; t < 5; t++) acc[t] = (f32x4){0.f, 0.f, 0.f, 0.f};

        #pragma unroll
        for (int kk = 0; kk < 4; kk++) {
            // A-frag direct from global: cols kk*32 + quad*8 .. +8
            bf16x8 af;
            if (ok) {
                float4 v0 = hrow[kk * 8 + quad * 2];
                float4 v1 = hrow[kk * 8 + quad * 2 + 1];
                af[0] = (__bf16)v0.x; af[1] = (__bf16)v0.y;
                af[2] = (__bf16)v0.z; af[3] = (__bf16)v0.w;
                af[4] = (__bf16)v1.x; af[5] = (__bf16)v1.y;
                af[6] = (__bf16)v1.z; af[7] = (__bf16)v1.w;
            } else {
                #pragma unroll
                for (int j = 0; j < 8; j++) af[j] = (__bf16)0.f;
            }
            #pragma unroll
            for (int t = 0; t < 5; t++) {
                bf16x8 bf = *(const bf16x8*)&Bt[(t * 16 + m) * PADK + kk * 32 + quad * 8];
                acc[t] = __builtin_amdgcn_mfma_f32_16x16x32_bf16(af, bf, acc[t], 0, 0, 0);
            }
        }

        // epilogue: D layout col=lane&15, row=quad*4+reg
        const int nodeb = tile * 64 + wv * 16 + quad * 4;
        #pragma unroll
        for (int r = 0; r < 4; r++) {
            int n = nodeb + r;
            if (n < N_NODES) {
                #pragma unroll
                for (int t = 0; t < 4; t++)
                    Whb[n * 64 + t * 16 + m] = __float2bfloat16(acc[t][r] + wb4[t]);
                float ev = acc[4][r] + eb;
                if (m < 4) es[n * 4 + m] = ev;
                else if (m >= 8 && m < 12) ed[n * 4 + (m - 8)] = ev;
            }
        }
    }
}

// ---------------------------------------------------------------------------
// Replaces k_csr + k_gather (and round-2's CAS-poisoned k_acc).
// One block per HALF-bucket (128 dst nodes): int-atomic LDS sort of the slab
// into a node-grouped list, then the proven k_gather sequential-FMA inner
// loop reading the edge list from LDS.  No FP atomics anywhere.
// 512 thr, ~21 KB LDS -> 4 blocks/CU resident.
// ---------------------------------------------------------------------------
__global__ __launch_bounds__(512) void k_bucket(
    const uint* __restrict__ sb, const int* __restrict__ gcur,
    const __hip_bfloat16* __restrict__ Whb, const float* __restrict__ es,
    const float* __restrict__ ed, float* __restrict__ out)
{
    __shared__ int ssl[CAPH];          // 11.3 KB node-grouped src list
    __shared__ int ncnt[128];          // per-node degree
    __shared__ int noff[128];          // per-node start in ssl
    __shared__ int ncur[128];          // scatter cursors
    __shared__ int wsum[2];
    __shared__ float pu_all[8][256];   // 8 KB per-wave p staging

    const int b  = blockIdx.x >> 1;
    const int hf = blockIdx.x & 1;
    const int t  = threadIdx.x;
    const int l  = t & 63;
    const int wid = t >> 6;            // 0..7

    const int ebase = b * CAPB;
    const int ecnt = min(gcur[b], CAPB);
    const int dlo = hf << 7;           // 0 or 128

    if (t < 128) ncnt[t] = 0;
    __syncthreads();

    // ---- count this half's nodes (int LDS atomics: hardware path) ----
    for (int i = t; i < ecnt; i += 512) {
        int dn = (int)(sb[ebase + i] >> 17) - dlo;
        if ((unsigned)dn < 128u) atomicAdd(&ncnt[dn], 1);
    }
    __syncthreads();

    // ---- inclusive scan of ncnt[0..127] (first 2 waves carry values) ----
    {
        int v = (t < 128) ? ncnt[t] : 0;
        int x = v;
        #pragma unroll
        for (int o = 1; o < 64; o <<= 1) {
            int y = __shfl_up(x, o);
            if (l >= o) x += y;
        }
        if (l == 63 && wid < 2) wsum[wid] = x;
        __syncthreads();
        if (t < 128) {
            int add = (wid == 1) ? wsum[0] : 0;
            int excl = x + add - v;
            noff[t] = excl;
            ncur[t] = excl;
        }
    }
    __syncthreads();

    // ---- scatter slab entries into node-grouped LDS list ----
    for (int i = t; i < ecnt; i += 512) {
        uint v = sb[ebase + i];
        int dn = (int)(v >> 17) - dlo;
        if ((unsigned)dn < 128u) {
            int pos = atomicAdd(&ncur[dn], 1);   // int returning LDS atomic
            if (pos < CAPH) ssl[pos] = (int)(v & 0x1FFFFu);
        }
    }
    __syncthreads();

    // ---- gather phase: 8 waves x 16 nodes, k_gather inner loop ----
    const int r = l & 15;              // lane-in-quarter: dims 4r..4r+3
    const int q = l >> 4;              // quarter = which edge of the 4-group
    const int hh = r >> 2;             // head of dims 4r..4r+3
    const float4* es4 = (const float4*)es;
    const uint2* Wu2 = (const uint2*)Whb;
    float* pu = &pu_all[wid][0];
    const float* pu_q = pu + q * 4 + hh;

    for (int k = 0; k < 16; k++) {
        const int ln = wid * 16 + k;
        const int node = b * 256 + dlo + ln;
        if (node >= N_NODES) break;    // nodes ascend within wave

        int start = noff[ln];
        int deg = ncnt[ln];
        if (start >= CAPH) deg = 0;            // overflow-drop safety
        else deg = min(deg, CAPH - start);

        const float4 edv = ((const float4*)ed)[node];

        float acc0 = 0.f, acc1 = 0.f, acc2 = 0.f, acc3 = 0.f, den = 0.f;

        for (int bst = 0; bst < deg; bst += 64) {
            int nchunk = min(64, deg - bst);

            float4 p4 = make_float4(0.f, 0.f, 0.f, 0.f);
            if (l < nchunk) {
                int sl = ssl[start + bst + l];
                float4 esv = es4[sl];
                float x;
                x = esv.x + edv.x; p4.x = __expf(fmaxf(x, GAT_ALPHA * x));
                x = esv.y + edv.y; p4.y = __expf(fmaxf(x, GAT_ALPHA * x));
                x = esv.z + edv.z; p4.z = __expf(fmaxf(x, GAT_ALPHA * x));
                x = esv.w + edv.w; p4.w = __expf(fmaxf(x, GAT_ALPHA * x));
            }
            ((float4*)pu)[l] = p4;     // zero-padded tail
            // single wave owns pu: wave-internal lgkm ordering, no barrier

            const int last = start + deg - 1;
            #pragma unroll 4
            for (int jj = 0; jj < nchunk; jj += 4) {
                int ee = min(start + bst + jj + q, last);  // clamp: tail p==0
                int s = ssl[ee];
                float p = pu_q[jj * 4];
                uint2 v = Wu2[s * 16 + r];
                acc0 = fmaf(p, __uint_as_float(v.x << 16), acc0);
                acc1 = fmaf(p, __uint_as_float(v.x & 0xffff0000u), acc1);
                acc2 = fmaf(p, __uint_as_float(v.y << 16), acc2);
                acc3 = fmaf(p, __uint_as_float(v.y & 0xffff0000u), acc3);
                den += p;
            }
        }

        acc0 += __shfl_xor(acc0, 16); acc1 += __shfl_xor(acc1, 16);
        acc2 += __shfl_xor(acc2, 16); acc3 += __shfl_xor(acc3, 16);
        den  += __shfl_xor(den, 16);
        acc0 += __shfl_xor(acc0, 32); acc1 += __shfl_xor(acc1, 32);
        acc2 += __shfl_xor(acc2, 32); acc3 += __shfl_xor(acc3, 32);
        den  += __shfl_xor(den, 32);

        if (q == 0) {
            float rr = 1.0f / fmaxf(den, 1e-9f);   // deg==0 -> 0, matches ref
            ((float4*)out)[node * 16 + r] =
                make_float4(acc0 * rr, acc1 * rr, acc2 * rr, acc3 * rr);
        }
    }
}

// ---------------------------------------------------------------------------
extern "C" void kernel_launch(void* const* d_in, const int* in_sizes, int n_in,
                              void* d_out, int out_size, void* d_ws, size_t ws_size,
                              hipStream_t stream)
{
    const float* h  = (const float*)d_in[0];
    const float* W  = (const float*)d_in[1];
    const float* Wb = (const float*)d_in[2];
    const float* a  = (const float*)d_in[3];
    const float* ab = (const float*)d_in[4];
    const int* src  = (const int*)d_in[5];
    const int* dst  = (const int*)d_in[6];
    float* out = (float*)d_out;

    char* w = (char*)d_ws;
    __hip_bfloat16* Whb = (__hip_bfloat16*)w; w += (size_t)N_NODES * 64 * 2;  // 12.8 MB
    float* es      = (float*)w;  w += (size_t)N_NODES * 4 * 4;     // 1.6 MB
    float* ed      = (float*)w;  w += (size_t)N_NODES * 4 * 4;     // 1.6 MB
    uint* sb       = (uint*)w;   w += (size_t)NBK * CAPB * 4;      // 8.0 MB
    int* gcur      = (int*)w;    w += 512 * 4;
    // total ~24 MB

    hipMemsetAsync(gcur, 0, NBK * sizeof(int), stream);
    k_fused<<<EBLK + PBLK, 256, 0, stream>>>(h, W, Wb, a, ab, src, dst,
                                             gcur, sb, Whb, es, ed);
    k_bucket<<<NBK * 2, 512, 0, stream>>>(sb, gcur, Whb, es, ed, out);
}

// Round 4
// 198.062 us; speedup vs baseline: 4.4389x; 1.0315x over previous
//
#include <hip/hip_runtime.h>
#include <hip/hip_bf16.h>
#include <math.h>

#define N_NODES 100000
#define N_EDGES 1600000
#define NF 128
#define NH 4
#define ND 16
#define GAT_ALPHA 0.2f

#define BSHIFT 8                      // bucket = dst >> 8 (256 nodes per bucket)
#define NBK 391                       // ceil(100000 / 256)
#define CAPB 5120                     // slab capacity per bucket (E[edges]=4096, sigma=64)
#define CAPH 2816                     // per half-bucket LDS list capacity (mean 2048 + 17 sigma)
#define EPB 8192                      // edges per placement block
#define EBLK 196                      // placement blocks (ceil(E / EPB))
#define PBLK 391                      // projection blocks (4 tiles each)
#define NTILES ((N_NODES + 63) / 64)  // 1563

typedef __attribute__((ext_vector_type(8))) __bf16 bf16x8;
typedef __attribute__((ext_vector_type(4))) float f32x4;

#define PADK 136                      // bf16 row stride (272B), breaks bank stride

// ---------------------------------------------------------------------------
// k_prep: one-time B-table build + gcur zeroing (replaces the memset launch).
// Btg layout (compact [80][128] bf16): rows 0..63 = W^T per head,
// rows 64+hh = W·a1, rows 72+hh = W·a2, rows 68..71 / 76..79 = zero.
// ---------------------------------------------------------------------------
__global__ __launch_bounds__(256) void k_prep(
    const float* __restrict__ W, const float* __restrict__ a,
    int* __restrict__ gcur, __hip_bfloat16* __restrict__ Btg)
{
    const int hh = blockIdx.x;        // 0..3 (one block per head)
    const int t = threadIdx.x;

    if (hh == 0)
        for (int i = t; i < 512; i += 256) gcur[i] = 0;

    // transpose W[hh] into rows hh*16+d
    for (int idx = t; idx < 2048; idx += 256) {
        int d = idx & 15, f = idx >> 4;
        Btg[(hh * 16 + d) * 128 + f] =
            __float2bfloat16(W[hh * (NF * ND) + f * ND + d]);
    }
    // dot rows: 64+hh (W·a1), 72+hh (W·a2)
    for (int idx = t; idx < 256; idx += 256) {
        int f = idx & 127, which = idx >> 7;
        float s = 0.f;
        #pragma unroll
        for (int d = 0; d < 16; d++)
            s = fmaf(W[hh * (NF * ND) + f * ND + d], a[hh * 32 + which * 16 + d], s);
        Btg[(64 + which * 8 + hh) * 128 + f] = __float2bfloat16(s);
    }
    // zero rows: 68+hh, 76+hh
    for (int idx = t; idx < 256; idx += 256) {
        int f = idx & 127, which = idx >> 7;
        Btg[(68 + which * 8 + hh) * 128 + f] = __float2bfloat16(0.f);
    }
}

// ---------------------------------------------------------------------------
// Fused kernel, role by blockIdx:
//   blocks [0, EBLK)      : bucket placement of edges into fixed slabs
//   blocks [EBLK, EBLK+PBLK): MFMA projection, 4 tiles/block, B staged by
//   a 20.5 KB vectorized copy from the precomputed Btg (no conversions).
// ---------------------------------------------------------------------------
__global__ __launch_bounds__(256) void k_fused(
    const float* __restrict__ h, const __hip_bfloat16* __restrict__ Btg,
    const float* __restrict__ Wb, const float* __restrict__ a,
    const float* __restrict__ ab, const int* __restrict__ src,
    const int* __restrict__ dst, int* __restrict__ gcur,
    uint* __restrict__ sb, __hip_bfloat16* __restrict__ Whb,
    float* __restrict__ es, float* __restrict__ ed)
{
    __shared__ __align__(16) __hip_bfloat16 Bt[80 * PADK];  // 21.8 KB (project)
    __shared__ int hist[NBK];                               // 1.6 KB (place)
    __shared__ int cur[NBK];                                // 1.6 KB (place)

    const int tid = threadIdx.x;

    if (blockIdx.x < EBLK) {
        // ---------------- role: bucket placement ------------------------
        const int base = blockIdx.x * EPB;
        const int lim = min(EPB, N_EDGES - base);

        for (int i = tid; i < NBK; i += 256) hist[i] = 0;
        __syncthreads();
        for (int i = tid; i < lim; i += 256)
            atomicAdd(&hist[dst[base + i] >> BSHIFT], 1);
        __syncthreads();
        for (int i = tid; i < NBK; i += 256) {
            int v = hist[i];
            cur[i] = v ? atomicAdd(&gcur[i], v) : 0;
        }
        __syncthreads();
        for (int i = tid; i < lim; i += 256) {
            int d = dst[base + i];
            int bk = d >> BSHIFT;
            int pos = atomicAdd(&cur[bk], 1);            // LDS returning atomic
            if (pos < CAPB)
                sb[bk * CAPB + pos] = (uint)(src[base + i] | ((d & 255) << 17));
        }
        return;
    }

    // ------------------- role: MFMA projection --------------------------
    const int pb = blockIdx.x - EBLK;    // 0..PBLK-1
    const int wv = tid >> 6;
    const int l = tid & 63;
    const int m = l & 15;
    const int quad = l >> 4;

    // stage B: plain vectorized copy of precomputed table (1280 float4)
    for (int c = tid; c < 80 * 128 / 8; c += 256) {
        int row = c >> 4, col = (c & 15) * 8;
        *(float4*)&Bt[row * PADK + col] = ((const float4*)Btg)[c];
    }

    float wb4[4];
    #pragma unroll
    for (int t = 0; t < 4; t++) wb4[t] = Wb[t * 16 + m];
    float eb = 0.f;
    if (m < 4) {
        #pragma unroll
        for (int d = 0; d < 16; d++) eb = fmaf(Wb[m * 16 + d], a[m * 32 + d], eb);
    } else if (m >= 8 && m < 12) {
        int hh = m - 8;
        #pragma unroll
        for (int d = 0; d < 16; d++)
            eb = fmaf(Wb[hh * 16 + d], a[hh * 32 + 16 + d], eb);
        eb += ab[hh];
    }
    __syncthreads();   // Bt visible; no per-tile barriers needed after this

    for (int tile = pb; tile < NTILES; tile += PBLK) {
        const int node = tile * 64 + wv * 16 + m;   // A row this lane serves
        const bool ok = node < N_NODES;
        const float4* hrow = (const float4*)(h + (size_t)(ok ? node : 0) * NF);

        f32x4 acc[5];
        #pragma unroll
        for (int t = 0; t < 5; t++) acc[t] = (f32x4){0.f, 0.f, 0.f, 0.f};

        #pragma unroll
        for (int kk = 0; kk < 4; kk++) {
            // A-frag direct from global: cols kk*32 + quad*8 .. +8
            bf16x8 af;
            if (ok) {
                float4 v0 = hrow[kk * 8 + quad * 2];
                float4 v1 = hrow[kk * 8 + quad * 2 + 1];
                af[0] = (__bf16)v0.x; af[1] = (__bf16)v0.y;
                af[2] = (__bf16)v0.z; af[3] = (__bf16)v0.w;
                af[4] = (__bf16)v1.x; af[5] = (__bf16)v1.y;
                af[6] = (__bf16)v1.z; af[7] = (__bf16)v1.w;
            } else {
                #pragma unroll
                for (int j = 0; j < 8; j++) af[j] = (__bf16)0.f;
            }
            #pragma unroll
            for (int t = 0; t < 5; t++) {
                bf16x8 bf = *(const bf16x8*)&Bt[(t * 16 + m) * PADK + kk * 32 + quad * 8];
                acc[t] = __builtin_amdgcn_mfma_f32_16x16x32_bf16(af, bf, acc[t], 0, 0, 0);
            }
        }

        // epilogue: D layout col=lane&15, row=quad*4+reg
        const int nodeb = tile * 64 + wv * 16 + quad * 4;
        #pragma unroll
        for (int r = 0; r < 4; r++) {
            int n = nodeb + r;
            if (n < N_NODES) {
                #pragma unroll
                for (int t = 0; t < 4; t++)
                    Whb[n * 64 + t * 16 + m] = __float2bfloat16(acc[t][r] + wb4[t]);
                float ev = acc[4][r] + eb;
                if (m < 4) es[n * 4 + m] = ev;
                else if (m >= 8 && m < 12) ed[n * 4 + (m - 8)] = ev;
            }
        }
    }
}

// ---------------------------------------------------------------------------
// One block per HALF-bucket (128 dst nodes): int-atomic LDS sort of the slab
// into a node-grouped list, then sequential-FMA per-node gather from LDS.
// (unchanged from round 3 — measured < 59.6 µs)
// ---------------------------------------------------------------------------
__global__ __launch_bounds__(512) void k_bucket(
    const uint* __restrict__ sb, const int* __restrict__ gcur,
    const __hip_bfloat16* __restrict__ Whb, const float* __restrict__ es,
    const float* __restrict__ ed, float* __restrict__ out)
{
    __shared__ int ssl[CAPH];          // 11.3 KB node-grouped src list
    __shared__ int ncnt[128];          // per-node degree
    __shared__ int noff[128];          // per-node start in ssl
    __shared__ int ncur[128];          // scatter cursors
    __shared__ int wsum[2];
    __shared__ float pu_all[8][256];   // 8 KB per-wave p staging

    const int b  = blockIdx.x >> 1;
    const int hf = blockIdx.x & 1;
    const int t  = threadIdx.x;
    const int l  = t & 63;
    const int wid = t >> 6;            // 0..7

    const int ebase = b * CAPB;
    const int ecnt = min(gcur[b], CAPB);
    const int dlo = hf << 7;           // 0 or 128

    if (t < 128) ncnt[t] = 0;
    __syncthreads();

    // ---- count this half's nodes (int LDS atomics: hardware path) ----
    for (int i = t; i < ecnt; i += 512) {
        int dn = (int)(sb[ebase + i] >> 17) - dlo;
        if ((unsigned)dn < 128u) atomicAdd(&ncnt[dn], 1);
    }
    __syncthreads();

    // ---- inclusive scan of ncnt[0..127] (first 2 waves carry values) ----
    {
        int v = (t < 128) ? ncnt[t] : 0;
        int x = v;
        #pragma unroll
        for (int o = 1; o < 64; o <<= 1) {
            int y = __shfl_up(x, o);
            if (l >= o) x += y;
        }
        if (l == 63 && wid < 2) wsum[wid] = x;
        __syncthreads();
        if (t < 128) {
            int add = (wid == 1) ? wsum[0] : 0;
            int excl = x + add - v;
            noff[t] = excl;
            ncur[t] = excl;
        }
    }
    __syncthreads();

    // ---- scatter slab entries into node-grouped LDS list ----
    for (int i = t; i < ecnt; i += 512) {
        uint v = sb[ebase + i];
        int dn = (int)(v >> 17) - dlo;
        if ((unsigned)dn < 128u) {
            int pos = atomicAdd(&ncur[dn], 1);   // int returning LDS atomic
            if (pos < CAPH) ssl[pos] = (int)(v & 0x1FFFFu);
        }
    }
    __syncthreads();

    // ---- gather phase: 8 waves x 16 nodes, sequential-FMA inner loop ----
    const int r = l & 15;              // lane-in-quarter: dims 4r..4r+3
    const int q = l >> 4;              // quarter = which edge of the 4-group
    const int hh = r >> 2;             // head of dims 4r..4r+3
    const float4* es4 = (const float4*)es;
    const uint2* Wu2 = (const uint2*)Whb;
    float* pu = &pu_all[wid][0];
    const float* pu_q = pu + q * 4 + hh;

    for (int k = 0; k < 16; k++) {
        const int ln = wid * 16 + k;
        const int node = b * 256 + dlo + ln;
        if (node >= N_NODES) break;    // nodes ascend within wave

        int start = noff[ln];
        int deg = ncnt[ln];
        if (start >= CAPH) deg = 0;            // overflow-drop safety
        else deg = min(deg, CAPH - start);

        const float4 edv = ((const float4*)ed)[node];

        float acc0 = 0.f, acc1 = 0.f, acc2 = 0.f, acc3 = 0.f, den = 0.f;

        for (int bst = 0; bst < deg; bst += 64) {
            int nchunk = min(64, deg - bst);

            float4 p4 = make_float4(0.f, 0.f, 0.f, 0.f);
            if (l < nchunk) {
                int sl = ssl[start + bst + l];
                float4 esv = es4[sl];
                float x;
                x = esv.x + edv.x; p4.x = __expf(fmaxf(x, GAT_ALPHA * x));
                x = esv.y + edv.y; p4.y = __expf(fmaxf(x, GAT_ALPHA * x));
                x = esv.z + edv.z; p4.z = __expf(fmaxf(x, GAT_ALPHA * x));
                x = esv.w + edv.w; p4.w = __expf(fmaxf(x, GAT_ALPHA * x));
            }
            ((float4*)pu)[l] = p4;     // zero-padded tail
            // single wave owns pu: wave-internal lgkm ordering, no barrier

            const int last = start + deg - 1;
            #pragma unroll 4
            for (int jj = 0; jj < nchunk; jj += 4) {
                int ee = min(start + bst + jj + q, last);  // clamp: tail p==0
                int s = ssl[ee];
                float p = pu_q[jj * 4];
                uint2 v = Wu2[s * 16 + r];
                acc0 = fmaf(p, __uint_as_float(v.x << 16), acc0);
                acc1 = fmaf(p, __uint_as_float(v.x & 0xffff0000u), acc1);
                acc2 = fmaf(p, __uint_as_float(v.y << 16), acc2);
                acc3 = fmaf(p, __uint_as_float(v.y & 0xffff0000u), acc3);
                den += p;
            }
        }

        acc0 += __shfl_xor(acc0, 16); acc1 += __shfl_xor(acc1, 16);
        acc2 += __shfl_xor(acc2, 16); acc3 += __shfl_xor(acc3, 16);
        den  += __shfl_xor(den, 16);
        acc0 += __shfl_xor(acc0, 32); acc1 += __shfl_xor(acc1, 32);
        acc2 += __shfl_xor(acc2, 32); acc3 += __shfl_xor(acc3, 32);
        den  += __shfl_xor(den, 32);

        if (q == 0) {
            float rr = 1.0f / fmaxf(den, 1e-9f);   // deg==0 -> 0, matches ref
            ((float4*)out)[node * 16 + r] =
                make_float4(acc0 * rr, acc1 * rr, acc2 * rr, acc3 * rr);
        }
    }
}

// ---------------------------------------------------------------------------
extern "C" void kernel_launch(void* const* d_in, const int* in_sizes, int n_in,
                              void* d_out, int out_size, void* d_ws, size_t ws_size,
                              hipStream_t stream)
{
    const float* h  = (const float*)d_in[0];
    const float* W  = (const float*)d_in[1];
    const float* Wb = (const float*)d_in[2];
    const float* a  = (const float*)d_in[3];
    const float* ab = (const float*)d_in[4];
    const int* src  = (const int*)d_in[5];
    const int* dst  = (const int*)d_in[6];
    float* out = (float*)d_out;

    char* w = (char*)d_ws;
    __hip_bfloat16* Whb = (__hip_bfloat16*)w; w += (size_t)N_NODES * 64 * 2;  // 12.8 MB
    float* es      = (float*)w;  w += (size_t)N_NODES * 4 * 4;     // 1.6 MB
    float* ed      = (float*)w;  w += (size_t)N_NODES * 4 * 4;     // 1.6 MB
    uint* sb       = (uint*)w;   w += (size_t)NBK * CAPB * 4;      // 8.0 MB
    int* gcur      = (int*)w;    w += 512 * 4;
    __hip_bfloat16* Btg = (__hip_bfloat16*)w; w += 80 * 128 * 2;   // 20.5 KB
    // total ~24 MB

    k_prep<<<4, 256, 0, stream>>>(W, a, gcur, Btg);
    k_fused<<<EBLK + PBLK, 256, 0, stream>>>(h, Btg, Wb, a, ab, src, dst,
                                             gcur, sb, Whb, es, ed);
    k_bucket<<<NBK * 2, 512, 0, stream>>>(sb, gcur, Whb, es, ed, out);
}